// Round 10
// baseline (303.246 us; speedup 1.0000x reference)
//
#include <hip/hip_runtime.h>

#define N_ENT   50000
#define CH      128
#define N_EDGES 1600000
#define N_RELM1 10
#define NB      391           // ceil(N_ENT / 128) buckets of 128 heads
#define BCAP    4608          // bucket capacity (verified r8: max bucket fits)
#define PART_BLOCKS 512
#define CHUNK   (N_EDGES / PART_BLOCKS)   // 3125 exactly (512*3125 = 1.6M)
#define EPS_N   1e-12f

__device__ __forceinline__ unsigned int f2bf_bits(float f) {
    unsigned int x = __float_as_uint(f);
    return (x + 0x7FFFu + ((x >> 16) & 1u)) >> 16;   // RNE; values are finite
}

// Per block: stage its 3125 edges in LDS bucket-binned, then COMPACT,
// COALESCED write-out to barr[blk*CHUNK ..]. Emits per-(block,bucket)
// counts and in-block offsets. Fused fp32->bf16x2 cvt of entity_emb.
// entry = tail(16) | rel(4)<<16 | hlow(7)<<20
__global__ __launch_bounds__(256) void gc_part_kernel(const int* __restrict__ head,
                                                      const int* __restrict__ tail,
                                                      const int* __restrict__ etyp,
                                                      int* __restrict__ barr,
                                                      int* __restrict__ cnts,
                                                      int* __restrict__ boffs,
                                                      const float* __restrict__ ent,
                                                      unsigned int* __restrict__ emb) {
    __shared__ int hist[512];     // NB bins padded to 512
    __shared__ int fctr[512];
    __shared__ int boff_s[512];
    __shared__ int psum[256];
    __shared__ int stage[CHUNK];  // 12.5 KB
    int tid = threadIdx.x, blk = blockIdx.x;
    for (int i = tid; i < 512; i += 256) { hist[i] = 0; fctr[i] = 0; }
    __syncthreads();
    int lo = blk * CHUNK;
    for (int e = lo + tid; e < lo + CHUNK; e += 256)
        atomicAdd(&hist[head[e] >> 7], 1);
    __syncthreads();
    // exclusive scan of 512 bins: 2 bins/thread + 256-ladder
    int a0 = hist[2 * tid], a1 = hist[2 * tid + 1];
    int s2 = a0 + a1;
    psum[tid] = s2;
    __syncthreads();
    for (int d = 1; d < 256; d <<= 1) {
        int t = (tid >= d) ? psum[tid - d] : 0;
        __syncthreads();
        psum[tid] += t;
        __syncthreads();
    }
    int excl = psum[tid] - s2;
    boff_s[2 * tid] = excl;
    boff_s[2 * tid + 1] = excl + a0;
    __syncthreads();
    // fill pass: LDS scatter into bucket-binned stage
    for (int e = lo + tid; e < lo + CHUNK; e += 256) {
        int h = head[e];
        int b = h >> 7;
        int pos = boff_s[b] + atomicAdd(&fctr[b], 1);
        stage[pos] = (tail[e] & 0xFFFF) | ((etyp[e] - 1) << 16) | ((h & 127) << 20);
    }
    __syncthreads();
    // compact, coalesced write-out
    for (int i = tid; i < CHUNK; i += 256) barr[lo + i] = stage[i];
    for (int i = tid; i < NB; i += 256) {
        cnts[blk * NB + i] = fctr[i];
        boffs[blk * NB + i] = boff_s[i];
    }
    // fused cvt (independent streaming work)
    for (int i = blk * 256 + tid; i < N_ENT * (CH / 2); i += PART_BLOCKS * 256) {
        float2 v = *(const float2*)(ent + 2 * (size_t)i);
        emb[i] = f2bf_bits(v.x) | (f2bf_bits(v.y) << 16);
    }
}

// per bucket (512 threads = one per part-block window): gather compact
// windows to LDS, per-head hist + scan, emit off_deg[h] = (start<<11)|deg,
// scatter head-sorted entries to csr.
__global__ __launch_bounds__(512) void gc_place_kernel(const int* __restrict__ barr,
                                                       const int* __restrict__ cnts,
                                                       const int* __restrict__ boffs,
                                                       unsigned int* __restrict__ off_deg,
                                                       int* __restrict__ csr) {
    __shared__ int ent_s[BCAP];
    __shared__ int psum[512];
    __shared__ int hcnt[128];
    __shared__ int hloc[128];
    __shared__ int hctr[128];
    int b = blockIdx.x, tid = threadIdx.x;
    if (tid < 128) { hcnt[tid] = 0; hctr[tid] = 0; }
    int c = cnts[tid * NB + b];
    int o = boffs[tid * NB + b];
    psum[tid] = c;
    __syncthreads();
    for (int d = 1; d < 512; d <<= 1) {
        int t = (tid >= d) ? psum[tid - d] : 0;
        __syncthreads();
        psum[tid] += t;
        __syncthreads();
    }
    int my_off = psum[tid] - c;
    int n = psum[511];
    const int* src = barr + tid * CHUNK + o;
    for (int k = 0; k < c; ++k) ent_s[my_off + k] = src[k];
    __syncthreads();
    for (int i = tid; i < n; i += 512)
        atomicAdd(&hcnt[(ent_s[i] >> 20) & 127], 1);
    __syncthreads();
    // exclusive scan over 128 heads (ladder, first 128 threads)
    int v = (tid < 128) ? hcnt[tid] : 0;
    for (int d = 1; d < 128; d <<= 1) {
        int t = (tid < 128 && tid >= d) ? hcnt[tid - d] : 0;
        __syncthreads();
        if (tid < 128) hcnt[tid] += t;
        __syncthreads();
    }
    int lo = b * BCAP;
    if (tid < 128) {
        int start = lo + hcnt[tid] - v;
        hloc[tid] = start;
        int h = (b << 7) + tid;
        if (h < N_ENT) off_deg[h] = ((unsigned)start << 11) | (unsigned)v;
    }
    __syncthreads();
    for (int i = tid; i < n; i += 512) {
        int e = ent_s[i];
        int hl = (e >> 20) & 127;
        int pos = hloc[hl] + atomicAdd(&hctr[hl], 1);
        csr[pos] = e & 0xFFFFF;
    }
}

// one wave64 per head row; scalarized edge metadata (SGPR tail/rel), bf16
// gather, fp32 accumulate; fused mean + L2-norm + bf16 dst + fp32 residual
__global__ __launch_bounds__(256) void gc_hop_kernel(
        const unsigned int* __restrict__ src,     // bf16x2 per uint
        const unsigned int* __restrict__ off_deg,
        const int* __restrict__ csr,
        const float* __restrict__ wt,
        unsigned int* __restrict__ dst,
        float* __restrict__ res,
        const float* __restrict__ ent,
        int init) {
    __shared__ float wt_s[N_RELM1 * CH];
    for (int i = threadIdx.x; i < N_RELM1 * CH; i += 256) wt_s[i] = wt[i];
    __syncthreads();

    int wave = threadIdx.x >> 6, lane = threadIdx.x & 63;
    int row = __builtin_amdgcn_readfirstlane(blockIdx.x * 4 + wave);
    // N_ENT % 4 == 0 and grid == N_ENT/4, so row < N_ENT always

    unsigned od = (unsigned)__builtin_amdgcn_readfirstlane((int)off_deg[row]);
    int seg = (int)(od >> 11);
    int deg = (int)(od & 2047u);
    int seg_end = seg + deg;

    float ax = 0.f, ay = 0.f;
    int j = seg;
    for (; j + 8 <= seg_end; j += 8) {
        int pk[8];
        #pragma unroll
        for (int u = 0; u < 8; ++u)
            pk[u] = __builtin_amdgcn_readfirstlane(csr[j + u]);
        #pragma unroll
        for (int u = 0; u < 8; ++u) {
            unsigned v = src[pk[u] % 65536 * 64 + lane];   // pk&0xFFFF scalar
            float2 w = *(const float2*)(&wt_s[(pk[u] >> 16) * CH + 2 * lane]);
            ax = fmaf(__uint_as_float(v << 16), w.x, ax);
            ay = fmaf(__uint_as_float(v & 0xFFFF0000u), w.y, ay);
        }
    }
    for (; j < seg_end; ++j) {
        int pk = __builtin_amdgcn_readfirstlane(csr[j]);
        unsigned v = src[pk % 65536 * 64 + lane];
        float2 w = *(const float2*)(&wt_s[(pk >> 16) * CH + 2 * lane]);
        ax = fmaf(__uint_as_float(v << 16), w.x, ax);
        ay = fmaf(__uint_as_float(v & 0xFFFF0000u), w.y, ay);
    }

    float invd = 1.0f / fmaxf((float)deg, 1.0f);
    float x0 = ax * invd, x1 = ay * invd;

    float s = x0 * x0 + x1 * x1;
    #pragma unroll
    for (int o = 32; o > 0; o >>= 1) s += __shfl_down(s, o, 64);
    s = __shfl(s, 0, 64);

    float inv = 1.0f / fmaxf(sqrtf(s), EPS_N);
    float y0 = x0 * inv, y1 = x1 * inv;

    dst[(row << 6) + lane] = f2bf_bits(y0) | (f2bf_bits(y1) << 16);

    int base = (row << 7) + 2 * lane;
    if (init) {
        float2 e = *(const float2*)(ent + base);
        *(float2*)(res + base) = make_float2(e.x + y0, e.y + y1);
    } else {
        float2 rv = *(const float2*)(res + base);
        *(float2*)(res + base) = make_float2(rv.x + y0, rv.y + y1);
    }
}

extern "C" void kernel_launch(void* const* d_in, const int* in_sizes, int n_in,
                              void* d_out, int out_size, void* d_ws, size_t ws_size,
                              hipStream_t stream) {
    const float* ent  = (const float*)d_in[0];
    const int*   eidx = (const int*)d_in[1];   // [2, E]: head row 0, tail row 1
    const int*   etyp = (const int*)d_in[2];
    const float* wt   = (const float*)d_in[3];
    float*       res  = (float*)d_out;

    const int* head = eidx;
    const int* tail = eidx + N_EDGES;

    // workspace layout (~42 MB)
    unsigned int* embA = (unsigned int*)d_ws;            // N_ENT*64 (bf16x2) 12.8 MB
    unsigned int* embB = embA + (size_t)N_ENT * 64;      // 12.8 MB
    int* barr  = (int*)(embB + (size_t)N_ENT * 64);      // N_EDGES 6.4 MB (compact)
    int* cnts  = barr + N_EDGES;                         // PART_BLOCKS*NB 0.8 MB
    int* boffs = cnts + PART_BLOCKS * NB;                // PART_BLOCKS*NB 0.8 MB
    unsigned int* off_deg = (unsigned int*)(boffs + PART_BLOCKS * NB); // N_ENT
    int* csr   = (int*)(off_deg + N_ENT);                // NB*BCAP 7.2 MB

    gc_part_kernel<<<PART_BLOCKS, 256, 0, stream>>>(head, tail, etyp, barr, cnts,
                                                    boffs, ent, embA);
    gc_place_kernel<<<NB, 512, 0, stream>>>(barr, cnts, boffs, off_deg, csr);

    const int hop_grid = N_ENT / 4;
    gc_hop_kernel<<<hop_grid, 256, 0, stream>>>(embA, off_deg, csr, wt, embB, res, ent, 1);
    gc_hop_kernel<<<hop_grid, 256, 0, stream>>>(embB, off_deg, csr, wt, embA, res, ent, 0);
    gc_hop_kernel<<<hop_grid, 256, 0, stream>>>(embA, off_deg, csr, wt, embB, res, ent, 0);
}

// Round 11
// 298.311 us; speedup vs baseline: 1.0165x; 1.0165x over previous
//
#include <hip/hip_runtime.h>

#define N_ENT   50000
#define CH      128
#define N_EDGES 1600000
#define N_RELM1 10
#define NB      391           // ceil(N_ENT / 128) buckets of 128 heads
#define BCAP    4608          // bucket capacity (verified r8: max bucket fits)
#define PART_BLOCKS 800
#define CHUNK   (N_EDGES / PART_BLOCKS)   // 2000 exactly
#define EPS_N   1e-12f

__device__ __forceinline__ unsigned int f2bf_bits(float f) {
    unsigned int x = __float_as_uint(f);
    return (x + 0x7FFFu + ((x >> 16) & 1u)) >> 16;   // RNE; values are finite
}

// Per block: ONE pass over its 2000 edges (read head/tail/etyp once, stage
// entry+bucket in LDS, histogram), scan, LDS bin-scatter, coalesced write-out.
// pack[blk*NB+b] = (in-block bucket offset << 8) | count. Fused cvt.
// entry = tail(16) | rel(4)<<16 | hlow(7)<<20
__global__ __launch_bounds__(256) void gc_part_kernel(const int* __restrict__ head,
                                                      const int* __restrict__ tail,
                                                      const int* __restrict__ etyp,
                                                      int* __restrict__ barr,
                                                      int* __restrict__ pack,
                                                      const float* __restrict__ ent,
                                                      unsigned int* __restrict__ emb) {
    __shared__ int hist[512];                // NB bins padded
    __shared__ int boff_s[512];
    __shared__ int fctr[512];
    __shared__ int psum[256];
    __shared__ int stageE[CHUNK];            // raw entries (8 KB)
    __shared__ unsigned short stageB[CHUNK]; // bucket ids (4 KB)
    __shared__ int stage2[CHUNK];            // binned entries (8 KB)
    int tid = threadIdx.x, blk = blockIdx.x;
    for (int i = tid; i < 512; i += 256) { hist[i] = 0; fctr[i] = 0; }
    __syncthreads();
    int lo = blk * CHUNK;
    // single global read pass: stage + histogram
    for (int i = tid; i < CHUNK; i += 256) {
        int e = lo + i;
        int h = head[e];
        int b = h >> 7;
        stageE[i] = (tail[e] & 0xFFFF) | ((etyp[e] - 1) << 16) | ((h & 127) << 20);
        stageB[i] = (unsigned short)b;
        atomicAdd(&hist[b], 1);
    }
    __syncthreads();
    // exclusive scan of 512 bins: 2 bins/thread + 256-ladder
    int a0 = hist[2 * tid], a1 = hist[2 * tid + 1];
    int s2 = a0 + a1;
    psum[tid] = s2;
    __syncthreads();
    for (int d = 1; d < 256; d <<= 1) {
        int t = (tid >= d) ? psum[tid - d] : 0;
        __syncthreads();
        psum[tid] += t;
        __syncthreads();
    }
    int excl = psum[tid] - s2;
    boff_s[2 * tid] = excl;
    boff_s[2 * tid + 1] = excl + a0;
    __syncthreads();
    // LDS -> LDS bin scatter
    for (int i = tid; i < CHUNK; i += 256) {
        int b = stageB[i];
        int pos = boff_s[b] + atomicAdd(&fctr[b], 1);
        stage2[pos] = stageE[i];
    }
    __syncthreads();
    // compact coalesced write-out + packed metadata
    for (int i = tid; i < CHUNK; i += 256) barr[lo + i] = stage2[i];
    for (int i = tid; i < NB; i += 256)
        pack[blk * NB + i] = (boff_s[i] << 8) | fctr[i];   // cnt <= ~30 << 255
    // fused cvt (independent streaming work)
    for (int i = blk * 256 + tid; i < N_ENT * (CH / 2); i += PART_BLOCKS * 256) {
        float2 v = *(const float2*)(ent + 2 * (size_t)i);
        emb[i] = f2bf_bits(v.x) | (f2bf_bits(v.y) << 16);
    }
}

// per bucket (1024 threads = one per part-block window): gather windows to
// LDS, per-head hist + scan, emit off_deg[h] = (start<<11)|deg, scatter
// head-sorted entries to csr.
__global__ __launch_bounds__(1024) void gc_place_kernel(const int* __restrict__ barr,
                                                        const int* __restrict__ pack,
                                                        unsigned int* __restrict__ off_deg,
                                                        int* __restrict__ csr) {
    __shared__ int ent_s[BCAP];
    __shared__ int psum[1024];
    __shared__ int hcnt[128];
    __shared__ int hloc[128];
    __shared__ int hctr[128];
    int b = blockIdx.x, tid = threadIdx.x;
    if (tid < 128) { hcnt[tid] = 0; hctr[tid] = 0; }
    int c = 0, o = 0;
    if (tid < PART_BLOCKS) {
        int pk = pack[tid * NB + b];
        c = pk & 255;
        o = pk >> 8;
    }
    psum[tid] = c;
    __syncthreads();
    for (int d = 1; d < 1024; d <<= 1) {
        int t = (tid >= d) ? psum[tid - d] : 0;
        __syncthreads();
        psum[tid] += t;
        __syncthreads();
    }
    int my_off = psum[tid] - c;
    int n = psum[1023];
    const int* src = barr + tid * CHUNK + o;
    for (int k = 0; k < c; ++k) ent_s[my_off + k] = src[k];
    __syncthreads();
    for (int i = tid; i < n; i += 1024)
        atomicAdd(&hcnt[(ent_s[i] >> 20) & 127], 1);
    __syncthreads();
    // exclusive scan over 128 heads (ladder on first 128 threads)
    int v = (tid < 128) ? hcnt[tid] : 0;
    for (int d = 1; d < 128; d <<= 1) {
        int t = (tid < 128 && tid >= d) ? hcnt[tid - d] : 0;
        __syncthreads();
        if (tid < 128) hcnt[tid] += t;
        __syncthreads();
    }
    int lo = b * BCAP;
    if (tid < 128) {
        int start = lo + hcnt[tid] - v;
        hloc[tid] = start;
        int h = (b << 7) + tid;
        if (h < N_ENT) off_deg[h] = ((unsigned)start << 11) | (unsigned)v;
    }
    __syncthreads();
    for (int i = tid; i < n; i += 1024) {
        int e = ent_s[i];
        int hl = (e >> 20) & 127;
        int pos = hloc[hl] + atomicAdd(&hctr[hl], 1);
        csr[pos] = e & 0xFFFFF;
    }
}

// one wave64 per head row; scalarized edge metadata (SGPR tail/rel), bf16
// gather, fp32 accumulate; fused mean + L2-norm + bf16 dst + fp32 residual
__global__ __launch_bounds__(256) void gc_hop_kernel(
        const unsigned int* __restrict__ src,     // bf16x2 per uint
        const unsigned int* __restrict__ off_deg,
        const int* __restrict__ csr,
        const float* __restrict__ wt,
        unsigned int* __restrict__ dst,
        float* __restrict__ res,
        const float* __restrict__ ent,
        int init) {
    __shared__ float wt_s[N_RELM1 * CH];
    for (int i = threadIdx.x; i < N_RELM1 * CH; i += 256) wt_s[i] = wt[i];
    __syncthreads();

    int wave = threadIdx.x >> 6, lane = threadIdx.x & 63;
    int row = __builtin_amdgcn_readfirstlane(blockIdx.x * 4 + wave);
    // N_ENT % 4 == 0 and grid == N_ENT/4, so row < N_ENT always

    unsigned od = (unsigned)__builtin_amdgcn_readfirstlane((int)off_deg[row]);
    int seg = (int)(od >> 11);
    int deg = (int)(od & 2047u);
    int seg_end = seg + deg;

    float ax = 0.f, ay = 0.f;
    int j = seg;
    for (; j + 8 <= seg_end; j += 8) {
        int pk[8];
        #pragma unroll
        for (int u = 0; u < 8; ++u)
            pk[u] = __builtin_amdgcn_readfirstlane(csr[j + u]);
        #pragma unroll
        for (int u = 0; u < 8; ++u) {
            unsigned v = src[pk[u] % 65536 * 64 + lane];   // pk&0xFFFF scalar
            float2 w = *(const float2*)(&wt_s[(pk[u] >> 16) * CH + 2 * lane]);
            ax = fmaf(__uint_as_float(v << 16), w.x, ax);
            ay = fmaf(__uint_as_float(v & 0xFFFF0000u), w.y, ay);
        }
    }
    for (; j < seg_end; ++j) {
        int pk = __builtin_amdgcn_readfirstlane(csr[j]);
        unsigned v = src[pk % 65536 * 64 + lane];
        float2 w = *(const float2*)(&wt_s[(pk >> 16) * CH + 2 * lane]);
        ax = fmaf(__uint_as_float(v << 16), w.x, ax);
        ay = fmaf(__uint_as_float(v & 0xFFFF0000u), w.y, ay);
    }

    float invd = 1.0f / fmaxf((float)deg, 1.0f);
    float x0 = ax * invd, x1 = ay * invd;

    float s = x0 * x0 + x1 * x1;
    #pragma unroll
    for (int o = 32; o > 0; o >>= 1) s += __shfl_down(s, o, 64);
    s = __shfl(s, 0, 64);

    float inv = 1.0f / fmaxf(sqrtf(s), EPS_N);
    float y0 = x0 * inv, y1 = x1 * inv;

    dst[(row << 6) + lane] = f2bf_bits(y0) | (f2bf_bits(y1) << 16);

    int base = (row << 7) + 2 * lane;
    if (init) {
        float2 e = *(const float2*)(ent + base);
        *(float2*)(res + base) = make_float2(e.x + y0, e.y + y1);
    } else {
        float2 rv = *(const float2*)(res + base);
        *(float2*)(res + base) = make_float2(rv.x + y0, rv.y + y1);
    }
}

extern "C" void kernel_launch(void* const* d_in, const int* in_sizes, int n_in,
                              void* d_out, int out_size, void* d_ws, size_t ws_size,
                              hipStream_t stream) {
    const float* ent  = (const float*)d_in[0];
    const int*   eidx = (const int*)d_in[1];   // [2, E]: head row 0, tail row 1
    const int*   etyp = (const int*)d_in[2];
    const float* wt   = (const float*)d_in[3];
    float*       res  = (float*)d_out;

    const int* head = eidx;
    const int* tail = eidx + N_EDGES;

    // workspace layout (~41 MB)
    unsigned int* embA = (unsigned int*)d_ws;            // N_ENT*64 (bf16x2) 12.8 MB
    unsigned int* embB = embA + (size_t)N_ENT * 64;      // 12.8 MB
    int* barr  = (int*)(embB + (size_t)N_ENT * 64);      // N_EDGES 6.4 MB (compact)
    int* pack  = barr + N_EDGES;                         // PART_BLOCKS*NB 1.25 MB
    unsigned int* off_deg = (unsigned int*)(pack + PART_BLOCKS * NB); // N_ENT
    int* csr   = (int*)(off_deg + N_ENT);                // NB*BCAP 7.2 MB

    gc_part_kernel<<<PART_BLOCKS, 256, 0, stream>>>(head, tail, etyp, barr, pack,
                                                    ent, embA);
    gc_place_kernel<<<NB, 1024, 0, stream>>>(barr, pack, off_deg, csr);

    const int hop_grid = N_ENT / 4;
    gc_hop_kernel<<<hop_grid, 256, 0, stream>>>(embA, off_deg, csr, wt, embB, res, ent, 1);
    gc_hop_kernel<<<hop_grid, 256, 0, stream>>>(embB, off_deg, csr, wt, embA, res, ent, 0);
    gc_hop_kernel<<<hop_grid, 256, 0, stream>>>(embA, off_deg, csr, wt, embB, res, ent, 0);
}